// Round 7
// baseline (29.036 us; speedup 1.0000x reference)
//
#include <hip/hip_runtime.h>
#include <hip/hip_bf16.h>

typedef __attribute__((ext_vector_type(8))) short bf16x8;
typedef __attribute__((ext_vector_type(4))) float f32x4;

static constexpr int Bb = 64;
static constexpr int Qq = 32;
static constexpr int LD = 4096;
static constexpr int Dd = 128;
static constexpr int SPLITS = 16;            // 1024 blocks
static constexpr int CHUNK = LD / SPLITS;    // 256 tokens per block
static constexpr int TILE = 32;              // tokens per LDS tile
static constexpr int ITERS = CHUNK / TILE;   // 8
static constexpr int TILE_BYTES = TILE * Dd * 4;  // 16 KB fp32
static constexpr int ROW_BYTES = Dd * 4;     // 512 B per token
static constexpr int NBUF = 3;               // pipeline depth-2 => 3 buffers (48 KB)

__device__ __forceinline__ short f2bf(float f) {
  __hip_bfloat16 h = __float2bfloat16(f);
  return *reinterpret_cast<short*>(&h);
}

__device__ __forceinline__ bf16x8 cvt8(float4 a, float4 b) {
  bf16x8 v;
  v[0] = f2bf(a.x); v[1] = f2bf(a.y); v[2] = f2bf(a.z); v[3] = f2bf(a.w);
  v[4] = f2bf(b.x); v[5] = f2bf(b.y); v[6] = f2bf(b.z); v[7] = f2bf(b.w);
  return v;
}

__device__ __forceinline__ void gload16(const void* g, void* l) {
  __builtin_amdgcn_global_load_lds(
      (const __attribute__((address_space(1))) void*)g,
      (__attribute__((address_space(3))) void*)l, 16, 0, 0);
}

#define WAIT_VMCNT(n) asm volatile("s_waitcnt vmcnt(" #n ")" ::: "memory")

// Stage 1: R6's contiguous gload_lds staging, upgraded from 2-buffer
// drain-to-zero to a 3-buffer counted-vmcnt pipeline (T3+T4, m201 template).
// Steady state: issue STAGE(it+2) -> wait vmcnt(8) (drains tile it only; 8
// loads stay in flight ACROSS the barrier) -> s_barrier -> compute tile it.
// Overwrite safety: barrier #it separates every wave's reads of buf[(it-1)%3]
// (iter it-1) from any wave's STAGE(it+2) into that same buffer (iter it).
// Epilogue drains 8 -> 4 -> 0. Absmax is the race detector (must stay 8.0).
__global__ __launch_bounds__(256) void maxsim_stage1(
    const float* __restrict__ qe, const float* __restrict__ de,
    float* __restrict__ pmax) {
  __shared__ __align__(16) char lds[NBUF][TILE_BYTES];

  const int blk  = blockIdx.x;
  const int b    = blk / SPLITS;
  const int s    = blk % SPLITS;
  const int wave = threadIdx.x >> 6;
  const int lane = threadIdx.x & 63;
  const int lcol = lane & 15;     // MFMA column slot
  const int lgrp = lane >> 4;     // MFMA k-group
  const int mt   = wave >> 1;     // this wave's 16-query M-tile (0/1)
  const int half = wave & 1;      // this wave's 16-token half of the 32-token tile

  const float* __restrict__ qb = qe + (size_t)b * Qq * Dd;
  const char*  __restrict__ dchunk =
      (const char*)(de + (size_t)b * LD * Dd) + (size_t)s * CHUNK * ROW_BYTES;

  // A fragment: one M-tile (16 query rows), registers for whole kernel.
  // Same lane->k rule as B, so any k-slot permutation cancels in the dot.
  bf16x8 afrag[4];
#pragma unroll
  for (int kb = 0; kb < 4; ++kb) {
    const float* p = qb + (size_t)(mt * 16 + lcol) * Dd + kb * 32 + lgrp * 8;
    afrag[kb] = cvt8(*reinterpret_cast<const float4*>(p),
                     *reinterpret_cast<const float4*>(p + 4));
  }

  // Stage tile `it` into buffer `bufi`: 4 instrs/wave x 1 KB, contiguous.
  // LDS written linearly (HW rule) from pre-swizzled global source:
  //   LDS[P] = global[P ^ ((rowof(P)&7)<<4)]; read applies the same XOR.
  auto STAGE = [&](int it, int bufi) {
    const char* itb = dchunk + (size_t)it * TILE_BYTES;
#pragma unroll
    for (int i = 0; i < 4; ++i) {
      unsigned P = (unsigned)(i * 4096 + wave * 1024 + lane * 16);
      unsigned G = P ^ (((P >> 9) & 7u) << 4);          // pre-swizzled source
      gload16(itb + G, &lds[bufi][i * 4096 + wave * 1024]);
    }
  };

  float mx[4];
#pragma unroll
  for (int i = 0; i < 4; ++i) mx[i] = -3.4e38f;

  const int row = half * 16 + lcol;                 // this lane's token row in tile
  const unsigned sw = ((unsigned)(lcol & 7)) << 4;  // row&7 == lcol&7

  // Compute one tile from buffer `bufi` (swizzled ds_read_b128, ~2-way banks).
  auto COMPUTE = [&](int bufi) {
    const char* base = &lds[bufi][row * ROW_BYTES];
    f32x4 acc = {0.f, 0.f, 0.f, 0.f};
#pragma unroll
    for (int kb = 0; kb < 4; ++kb) {
      unsigned o0 = ((unsigned)(kb * 128 + lgrp * 32)) ^ sw;
      unsigned o1 = ((unsigned)(kb * 128 + lgrp * 32 + 16)) ^ sw;
      float4 f0 = *reinterpret_cast<const float4*>(base + o0);
      float4 f1 = *reinterpret_cast<const float4*>(base + o1);
      bf16x8 bf = cvt8(f0, f1);
      acc = __builtin_amdgcn_mfma_f32_16x16x32_bf16(afrag[kb], bf, acc, 0, 0, 0);
    }
    // C/D layout (m89-verified): col = lane&15 (doc token), row = lgrp*4+i.
#pragma unroll
    for (int i = 0; i < 4; ++i) mx[i] = fmaxf(mx[i], acc[i]);
  };

  // Prologue: two tiles in flight.
  STAGE(0, 0);
  STAGE(1, 1);

  // Main loop: it = 0 .. ITERS-3 (stages tiles 2..ITERS-1).
  int nb = 2;  // buffer index of tile it+2
  int cb = 0;  // buffer index of tile it
  for (int it = 0; it < ITERS - 2; ++it) {
    STAGE(it + 2, nb);
    WAIT_VMCNT(8);                     // tile `it` landed; 8 loads stay in flight
    __builtin_amdgcn_s_barrier();
    asm volatile("" ::: "memory");
    COMPUTE(cb);
    nb = (nb == 2) ? 0 : nb + 1;
    cb = (cb == 2) ? 0 : cb + 1;
  }
  // Epilogue iter ITERS-2: only tile ITERS-1's 4 loads may remain in flight.
  WAIT_VMCNT(4);
  __builtin_amdgcn_s_barrier();
  asm volatile("" ::: "memory");
  COMPUTE(cb);
  cb = (cb == 2) ? 0 : cb + 1;
  // Epilogue iter ITERS-1: full drain.
  WAIT_VMCNT(0);
  __builtin_amdgcn_s_barrier();
  asm volatile("" ::: "memory");
  COMPUTE(cb);

  // Max over this wave's 16 doc-token columns = butterfly over low 4 lane bits.
#pragma unroll
  for (int off = 1; off < 16; off <<= 1)
#pragma unroll
    for (int i = 0; i < 4; ++i) mx[i] = fmaxf(mx[i], __shfl_xor(mx[i], off));

  __shared__ float smax[4][16];   // [wave = mt*2+half][q-row within M-tile]
  if (lcol == 0) {
#pragma unroll
    for (int i = 0; i < 4; ++i) smax[wave][lgrp * 4 + i] = mx[i];
  }
  __syncthreads();
  if (threadIdx.x < Qq) {
    const int qi = threadIdx.x;
    const int qmt = qi >> 4, qr = qi & 15;
    float m = fmaxf(smax[qmt * 2 + 0][qr], smax[qmt * 2 + 1][qr]);
    pmax[((size_t)b * SPLITS + s) * Qq + qi] = m;
  }
}

// Stage 2: out[b] = sum_q max_s pmax[b][s][q]. One wave per batch.
__global__ __launch_bounds__(64) void maxsim_stage2(
    const float* __restrict__ pmax, float* __restrict__ out) {
  const int b = blockIdx.x;
  const int lane = threadIdx.x;
  float v = 0.f;
  if (lane < Qq) {
    float m = -3.4e38f;
#pragma unroll
    for (int s = 0; s < SPLITS; ++s)
      m = fmaxf(m, pmax[((size_t)b * SPLITS + s) * Qq + lane]);
    v = m;
  }
#pragma unroll
  for (int off = 1; off < 64; off <<= 1) v += __shfl_xor(v, off);
  if (lane == 0) out[b] = v;
}

extern "C" void kernel_launch(void* const* d_in, const int* in_sizes, int n_in,
                              void* d_out, int out_size, void* d_ws, size_t ws_size,
                              hipStream_t stream) {
  const float* qe = (const float*)d_in[0];  // [64,32,128] f32
  const float* de = (const float*)d_in[1];  // [64,4096,128] f32
  float* out  = (float*)d_out;              // [64] f32
  float* pmax = (float*)d_ws;               // [64][16][32] f32 = 128 KB

  maxsim_stage1<<<Bb * SPLITS, 256, 0, stream>>>(qe, de, pmax);
  maxsim_stage2<<<Bb, 64, 0, stream>>>(pmax, out);
}